// Round 1
// baseline (19090.753 us; speedup 1.0000x reference)
//
#include <hip/hip_runtime.h>
#include <stdint.h>

#define Bsz 256
#define Tsz 512
#define Isz 512
#define Hsz 1024

typedef __attribute__((ext_vector_type(8))) short short8;
typedef __attribute__((ext_vector_type(4))) float f32x4;

// ws layout
static constexpr size_t XBF_OFF  = 0;                    // x bf16 [T][B][I]   = 128 MB
static constexpr size_t WIBF_OFF = 134217728;            // W_ih bf16 [4096][512] = 4 MB
static constexpr size_t HBUF_OFF = 138412032;            // h double buf bf16 [2][B][H] = 1 MB
static constexpr size_t FLAG_OFF = 139460608;            // 256 flags * 16 uints = 16 KB
static constexpr size_t WS_NEED  = 139476992;

__device__ __forceinline__ unsigned short f2bf(float f) {
  union { float f; unsigned u; } v; v.f = f;
  unsigned r = v.u + 0x7fff + ((v.u >> 16) & 1);   // RNE
  return (unsigned short)(r >> 16);
}

__device__ __forceinline__ void cvt8(const float* __restrict__ s, unsigned short* __restrict__ d) {
  float4 a = *(const float4*)s;
  float4 b = *(const float4*)(s + 4);
  union { unsigned short us[8]; uint4 v; } o;
  o.us[0] = f2bf(a.x); o.us[1] = f2bf(a.y); o.us[2] = f2bf(a.z); o.us[3] = f2bf(a.w);
  o.us[4] = f2bf(b.x); o.us[5] = f2bf(b.y); o.us[6] = f2bf(b.z); o.us[7] = f2bf(b.w);
  *(uint4*)d = o.v;
}

// ---------------------------------------------------------------------------
// Init: x [B][T][I] fp32 -> xbf [T][B][I] bf16 ; W_ih fp32 -> bf16 ; zero h/flags
// grid = 32768 (transpose) + 1024 (Wi cvt) + 260 (zero) = 34052 blocks x 256
// ---------------------------------------------------------------------------
__global__ __launch_bounds__(256)
void init_kernel(const float* __restrict__ x, const float* __restrict__ Wi,
                 unsigned char* __restrict__ ws)
{
  unsigned short* xbf  = (unsigned short*)(ws + XBF_OFF);
  unsigned short* wibf = (unsigned short*)(ws + WIBF_OFF);
  const int bid = blockIdx.x;
  const int tid = threadIdx.x;

  if (bid < 32768) {
    // 4 (t,b) rows per block; 64 threads per row, 8 elems per thread
    const int rowid = bid * 4 + (tid >> 6);      // rowid = t*256 + b
    const int t = rowid >> 8;
    const int b = rowid & 255;
    const int i = (tid & 63) * 8;
    const float* src = x + ((size_t)b * Tsz + t) * Isz + i;
    unsigned short* dst = xbf + (size_t)rowid * Isz + i;
    cvt8(src, dst);
  } else if (bid < 32768 + 1024) {
    // W_ih: 4096*512 = 2M floats; 2048 per block
    const size_t base = (size_t)(bid - 32768) * 2048 + (size_t)tid * 8;
    cvt8(Wi + base, wibf + base);
  } else {
    // zero h_buf (1 MB) + flags (16 KB) = 66560 x 16B chunks
    const int z = bid - 33792;                    // 0..259
    uint4 zero = make_uint4(0u, 0u, 0u, 0u);
    for (size_t j = (size_t)z * 256 + tid; j < 66560; j += (size_t)260 * 256)
      ((uint4*)(ws + HBUF_OFF))[j] = zero;
  }
}

// ---------------------------------------------------------------------------
// Persistent LSTM: 256 WGs (4 row-groups x 64 hidden-groups), 256 threads.
// Wave = 16 batch rows x 64 gate cols (4 MFMA col-tiles, one per gate).
// ---------------------------------------------------------------------------
__global__ __launch_bounds__(256, 1)
void lstm_persistent(const float* __restrict__ Wh,
                     const float* __restrict__ b_ih, const float* __restrict__ b_hh,
                     const float* __restrict__ c0, float* __restrict__ out,
                     unsigned char* __restrict__ ws)
{
  const unsigned short* __restrict__ xbf  = (const unsigned short*)(ws + XBF_OFF);
  const unsigned short* __restrict__ wibf = (const unsigned short*)(ws + WIBF_OFF);
  unsigned short* __restrict__ hbuf = (unsigned short*)(ws + HBUF_OFF);
  unsigned* __restrict__ flags = (unsigned*)(ws + FLAG_OFF);

  // [n][k] slice of W_hh, n = q*16+u (gate-major). +8 pad -> 2-way LDS aliasing (free).
  __shared__ unsigned short WhT[64][1032];
  __shared__ float bias[64];

  const int tid  = threadIdx.x;
  const int bid  = blockIdx.x;
  const int cg   = bid & 63;        // hidden-unit group: units [cg*16, cg*16+16)
  const int rg   = bid >> 6;        // batch-row group: rows [rg*64, rg*64+64)
  const int wv   = tid >> 6;        // wave 0..3
  const int lane = tid & 63;
  const int l16  = lane & 15;
  const int quad = lane >> 4;

  // ---- stage W_hh slice (fp32 -> bf16) into LDS ----
  {
    const int n  = tid >> 2;                       // 0..63
    const int q  = n >> 4, u = n & 15;
    const int gc = q * 1024 + cg * 16 + u;         // global gate row in W_hh
    const int k0 = (tid & 3) * 256;
    const float* src = Wh + (size_t)gc * Hsz + k0;
    unsigned short* dst = &WhT[n][k0];
    #pragma unroll 4
    for (int k = 0; k < 256; k += 8) cvt8(src + k, dst + k);
  }
  if (tid < 64) {
    const int q = tid >> 4, u = tid & 15;
    const int gc = q * 1024 + cg * 16 + u;
    bias[tid] = b_ih[gc] + b_hh[gc];
  }
  __syncthreads();

  const int rowbase = rg * 64 + wv * 16;           // first batch row of this wave
  const int arow    = rowbase + l16;               // A-fragment row for this lane
  const int hcol    = cg * 16 + l16;               // hidden unit owned by this lane

  // cell state lives in registers: rows rowbase+quad*4+r, unit hcol
  float creg[4];
  #pragma unroll
  for (int r = 0; r < 4; ++r)
    creg[r] = c0[(size_t)(rowbase + quad * 4 + r) * Hsz + hcol];

  // W_ih B-fragment row pointers (one per gate), bf16 [gc][k]
  const unsigned short* bp[4];
  #pragma unroll
  for (int q = 0; q < 4; ++q)
    bp[q] = wibf + (size_t)(q * 1024 + cg * 16 + l16) * Isz + quad * 8;

  int p = 0;
  for (int t = 0; t < Tsz; ++t) {
    const unsigned short* xt = xbf  + (size_t)t * Bsz * Isz + (size_t)arow * Isz + quad * 8;
    const unsigned short* hp = hbuf + (size_t)p * Bsz * Hsz + (size_t)arow * Hsz + quad * 8;

    f32x4 acc[4];
    #pragma unroll
    for (int q = 0; q < 4; ++q) acc[q] = (f32x4){0.f, 0.f, 0.f, 0.f};

    // ---- x @ W_ih^T partial (independent of h -> overlaps barrier wait) ----
    #pragma unroll 4
    for (int ks = 0; ks < 16; ++ks) {
      const int kk = ks * 32;
      short8 av = *(const short8*)(xt + kk);
      short8 b0 = *(const short8*)(bp[0] + kk);
      short8 b1 = *(const short8*)(bp[1] + kk);
      short8 b2 = *(const short8*)(bp[2] + kk);
      short8 b3 = *(const short8*)(bp[3] + kk);
      acc[0] = __builtin_amdgcn_mfma_f32_16x16x32_bf16(av, b0, acc[0], 0, 0, 0);
      acc[1] = __builtin_amdgcn_mfma_f32_16x16x32_bf16(av, b1, acc[1], 0, 0, 0);
      acc[2] = __builtin_amdgcn_mfma_f32_16x16x32_bf16(av, b2, acc[2], 0, 0, 0);
      acc[3] = __builtin_amdgcn_mfma_f32_16x16x32_bf16(av, b3, acc[3], 0, 0, 0);
    }

    // ---- wait for h_t (all WGs posted flag >= t) ----
    if (t > 0) {
      const unsigned tgt = (unsigned)t;
      unsigned v;
      do {
        v = __hip_atomic_load(&flags[(tid & 255) * 16], __ATOMIC_RELAXED,
                              __HIP_MEMORY_SCOPE_AGENT);
      } while (v < tgt);
      __threadfence();   // acquire: invalidate stale h lines in this XCD's L2
    }
    __syncthreads();     // all 4 waves' flag subsets verified

    // ---- h @ W_hh^T ----
    #pragma unroll 8
    for (int ks = 0; ks < 32; ++ks) {
      const int kk = ks * 32;
      short8 av = *(const short8*)(hp + kk);
      short8 b0 = *(const short8*)(&WhT[l16     ][kk + quad * 8]);
      short8 b1 = *(const short8*)(&WhT[16 + l16][kk + quad * 8]);
      short8 b2 = *(const short8*)(&WhT[32 + l16][kk + quad * 8]);
      short8 b3 = *(const short8*)(&WhT[48 + l16][kk + quad * 8]);
      acc[0] = __builtin_amdgcn_mfma_f32_16x16x32_bf16(av, b0, acc[0], 0, 0, 0);
      acc[1] = __builtin_amdgcn_mfma_f32_16x16x32_bf16(av, b1, acc[1], 0, 0, 0);
      acc[2] = __builtin_amdgcn_mfma_f32_16x16x32_bf16(av, b2, acc[2], 0, 0, 0);
      acc[3] = __builtin_amdgcn_mfma_f32_16x16x32_bf16(av, b3, acc[3], 0, 0, 0);
    }

    // ---- epilogue: gates -> c,h (all in-lane; C/D col=lane&15 == unit u) ----
    unsigned short* hn = hbuf + (size_t)(p ^ 1) * Bsz * Hsz;
    #pragma unroll
    for (int r = 0; r < 4; ++r) {
      float gi = acc[0][r] + bias[l16];
      float gf = acc[1][r] + bias[16 + l16];
      float gg = acc[2][r] + bias[32 + l16];
      float go = acc[3][r] + bias[48 + l16];
      float si = 1.f / (1.f + __expf(-gi));
      float sf = 1.f / (1.f + __expf(-gf));
      float tg = 1.f - 2.f / (__expf(2.f * gg) + 1.f);
      float so = 1.f / (1.f + __expf(-go));
      float cn = sf * creg[r] + si * tg;
      creg[r] = cn;
      float tc = 1.f - 2.f / (__expf(2.f * cn) + 1.f);
      hn[(size_t)(rowbase + quad * 4 + r) * Hsz + hcol] = f2bf(so * tc);
    }

    // ---- arrive: h_{t+1} published ----
    __syncthreads();     // drains all waves' h stores to L2 (vmcnt(0) before s_barrier)
    if (tid == 0)
      __hip_atomic_store(&flags[bid * 16], (unsigned)(t + 1), __ATOMIC_RELEASE,
                         __HIP_MEMORY_SCOPE_AGENT);   // release: wbl2 -> LLC
    p ^= 1;
  }

  // ---- final cell state ----
  #pragma unroll
  for (int r = 0; r < 4; ++r)
    out[(size_t)(rowbase + quad * 4 + r) * Hsz + hcol] = creg[r];
}

extern "C" void kernel_launch(void* const* d_in, const int* in_sizes, int n_in,
                              void* d_out, int out_size, void* d_ws, size_t ws_size,
                              hipStream_t stream) {
  const float* x   = (const float*)d_in[0];
  const float* Wi  = (const float*)d_in[1];
  const float* Wh  = (const float*)d_in[2];
  const float* bih = (const float*)d_in[3];
  const float* bhh = (const float*)d_in[4];
  const float* c0  = (const float*)d_in[5];
  float* out = (float*)d_out;
  unsigned char* ws = (unsigned char*)d_ws;

  if (ws_size < WS_NEED) return;  // fail visibly rather than corrupt memory

  init_kernel<<<34052, 256, 0, stream>>>(x, Wi, ws);

  void* args[] = { (void*)&Wh, (void*)&bih, (void*)&bhh,
                   (void*)&c0, (void*)&out, (void*)&ws };
  hipLaunchCooperativeKernel((void*)lstm_persistent, dim3(256), dim3(256),
                             args, 0, stream);
}

// Round 2
// 12218.186 us; speedup vs baseline: 1.5625x; 1.5625x over previous
//
#include <hip/hip_runtime.h>
#include <stdint.h>

#define Bsz 256
#define Tsz 512
#define Isz 512
#define Hsz 1024

typedef __attribute__((ext_vector_type(8))) short short8;
typedef __attribute__((ext_vector_type(4))) float f32x4;

// ws layout
static constexpr size_t XBF_OFF  = 0;                    // x bf16 [T][B][I]   = 128 MB
static constexpr size_t WIBF_OFF = 134217728;            // W_ih bf16 [4096][512] = 4 MB
static constexpr size_t HBUF_OFF = 138412032;            // h double buf bf16 [2][B][H] = 1 MB
static constexpr size_t FLAG_OFF = 139460608;            // 8 counters, 64 B apart
static constexpr size_t WS_NEED  = 139476992;

__device__ __forceinline__ unsigned short f2bf(float f) {
  union { float f; unsigned u; } v; v.f = f;
  unsigned r = v.u + 0x7fff + ((v.u >> 16) & 1);   // RNE
  return (unsigned short)(r >> 16);
}

__device__ __forceinline__ void cvt8(const float* __restrict__ s, unsigned short* __restrict__ d) {
  float4 a = *(const float4*)s;
  float4 b = *(const float4*)(s + 4);
  union { unsigned short us[8]; uint4 v; } o;
  o.us[0] = f2bf(a.x); o.us[1] = f2bf(a.y); o.us[2] = f2bf(a.z); o.us[3] = f2bf(a.w);
  o.us[4] = f2bf(b.x); o.us[5] = f2bf(b.y); o.us[6] = f2bf(b.z); o.us[7] = f2bf(b.w);
  *(uint4*)d = o.v;
}

// L2-bypassing h-fragment load: two 8-byte relaxed agent-scope atomic loads.
// Agent scope => sc-bit L2 bypass (per-XCD L2s are non-coherent), served by the
// memory-side LLC which is coherent by construction. Relaxed => NO buffer_inv.
__device__ __forceinline__ short8 ld_h(const unsigned short* p) {
  unsigned long long lo = __hip_atomic_load((unsigned long long*)(void*)p,
                                            __ATOMIC_RELAXED, __HIP_MEMORY_SCOPE_AGENT);
  unsigned long long hi = __hip_atomic_load((unsigned long long*)(void*)(p + 4),
                                            __ATOMIC_RELAXED, __HIP_MEMORY_SCOPE_AGENT);
  union { unsigned long long q[2]; short8 s; } u;
  u.q[0] = lo; u.q[1] = hi;
  return u.s;
}

// ---------------------------------------------------------------------------
// Init: x [B][T][I] fp32 -> xbf [T][B][I] bf16 ; W_ih fp32 -> bf16 ; zero h/flags
// ---------------------------------------------------------------------------
__global__ __launch_bounds__(256)
void init_kernel(const float* __restrict__ x, const float* __restrict__ Wi,
                 unsigned char* __restrict__ ws)
{
  unsigned short* xbf  = (unsigned short*)(ws + XBF_OFF);
  unsigned short* wibf = (unsigned short*)(ws + WIBF_OFF);
  const int bid = blockIdx.x;
  const int tid = threadIdx.x;

  if (bid < 32768) {
    const int rowid = bid * 4 + (tid >> 6);      // rowid = t*256 + b
    const int t = rowid >> 8;
    const int b = rowid & 255;
    const int i = (tid & 63) * 8;
    const float* src = x + ((size_t)b * Tsz + t) * Isz + i;
    unsigned short* dst = xbf + (size_t)rowid * Isz + i;
    cvt8(src, dst);
  } else if (bid < 32768 + 1024) {
    const size_t base = (size_t)(bid - 32768) * 2048 + (size_t)tid * 8;
    cvt8(Wi + base, wibf + base);
  } else {
    // zero h_buf (1 MB) + flags (16 KB) = 66560 x 16B chunks
    const int z = bid - 33792;                    // 0..259
    uint4 zero = make_uint4(0u, 0u, 0u, 0u);
    for (size_t j = (size_t)z * 256 + tid; j < 66560; j += (size_t)260 * 256)
      ((uint4*)(ws + HBUF_OFF))[j] = zero;
  }
}

// ---------------------------------------------------------------------------
// Persistent LSTM: 256 WGs (4 row-groups x 64 hidden-groups), 256 threads.
// Wave = 16 batch rows x 64 gate cols. 1 wave/SIMD -> latency hiding is ILP.
// ---------------------------------------------------------------------------
__global__ __launch_bounds__(256, 1)
void lstm_persistent(const float* __restrict__ Wh,
                     const float* __restrict__ b_ih, const float* __restrict__ b_hh,
                     const float* __restrict__ c0, float* __restrict__ out,
                     unsigned char* __restrict__ ws)
{
  const unsigned short* __restrict__ xbf  = (const unsigned short*)(ws + XBF_OFF);
  const unsigned short* __restrict__ wibf = (const unsigned short*)(ws + WIBF_OFF);
  unsigned short* __restrict__ hbuf = (unsigned short*)(ws + HBUF_OFF);
  unsigned* __restrict__ flags = (unsigned*)(ws + FLAG_OFF);

  __shared__ unsigned short WhT[64][1032];   // +8 pad: stride%32words==4 -> 2-way (free)
  __shared__ float bias[64];

  const int tid  = threadIdx.x;
  const int bid  = blockIdx.x;
  const int cg   = bid & 63;
  const int rg   = bid >> 6;
  const int wv   = tid >> 6;
  const int lane = tid & 63;
  const int l16  = lane & 15;
  const int quad = lane >> 4;

  // ---- stage W_hh slice (fp32 -> bf16) into LDS ----
  {
    const int n  = tid >> 2;
    const int q  = n >> 4, u = n & 15;
    const int gc = q * 1024 + cg * 16 + u;
    const int k0 = (tid & 3) * 256;
    const float* src = Wh + (size_t)gc * Hsz + k0;
    unsigned short* dst = &WhT[n][k0];
    #pragma unroll 4
    for (int k = 0; k < 256; k += 8) cvt8(src + k, dst + k);
  }
  if (tid < 64) {
    const int q = tid >> 4, u = tid & 15;
    const int gc = q * 1024 + cg * 16 + u;
    bias[tid] = b_ih[gc] + b_hh[gc];
  }
  __syncthreads();

  const int rowbase = rg * 64 + wv * 16;
  const int arow    = rowbase + l16;
  const int hcol    = cg * 16 + l16;

  float creg[4];
  #pragma unroll
  for (int r = 0; r < 4; ++r)
    creg[r] = c0[(size_t)(rowbase + quad * 4 + r) * Hsz + hcol];

  const unsigned short* bp[4];
  #pragma unroll
  for (int q = 0; q < 4; ++q)
    bp[q] = wibf + (size_t)(q * 1024 + cg * 16 + l16) * Isz + quad * 8;

  int p = 0;
  for (int t = 0; t < Tsz; ++t) {
    const unsigned short* xt = xbf  + (size_t)t * Bsz * Isz + (size_t)arow * Isz + quad * 8;
    const unsigned short* hp = hbuf + (size_t)p * Bsz * Hsz + (size_t)arow * Hsz + quad * 8;

    f32x4 acc[4];
    #pragma unroll
    for (int q = 0; q < 4; ++q) acc[q] = (f32x4){0.f, 0.f, 0.f, 0.f};

    // ---- x @ W_ih^T partial (no h dependency -> overlaps arrival skew) ----
    #pragma unroll 4
    for (int ks = 0; ks < 16; ++ks) {
      const int kk = ks * 32;
      short8 av = *(const short8*)(xt + kk);
      short8 b0 = *(const short8*)(bp[0] + kk);
      short8 b1 = *(const short8*)(bp[1] + kk);
      short8 b2 = *(const short8*)(bp[2] + kk);
      short8 b3 = *(const short8*)(bp[3] + kk);
      acc[0] = __builtin_amdgcn_mfma_f32_16x16x32_bf16(av, b0, acc[0], 0, 0, 0);
      acc[1] = __builtin_amdgcn_mfma_f32_16x16x32_bf16(av, b1, acc[1], 0, 0, 0);
      acc[2] = __builtin_amdgcn_mfma_f32_16x16x32_bf16(av, b2, acc[2], 0, 0, 0);
      acc[3] = __builtin_amdgcn_mfma_f32_16x16x32_bf16(av, b3, acc[3], 0, 0, 0);
    }

    // ---- wait: all 256 WGs posted step t-1 (8 counters, wave 0 polls) ----
    if (t > 0 && tid < 64) {
      const unsigned tgt = 32u * (unsigned)t;
      unsigned* f = &flags[(tid & 7) * 16];
      while (__hip_atomic_load(f, __ATOMIC_RELAXED, __HIP_MEMORY_SCOPE_AGENT) < tgt)
        __builtin_amdgcn_s_sleep(1);
    }
    __syncthreads();

    // ---- h @ W_hh^T, depth-8 ILP prefetch on the LLC h loads ----
    short8 hv[8];
    #pragma unroll
    for (int j = 0; j < 8; ++j) hv[j] = ld_h(hp + j * 32);

    #pragma unroll
    for (int ks = 0; ks < 32; ++ks) {
      short8 av = hv[ks & 7];
      if (ks + 8 < 32) hv[ks & 7] = ld_h(hp + (ks + 8) * 32);
      const int kk = ks * 32;
      short8 b0 = *(const short8*)(&WhT[l16     ][kk + quad * 8]);
      short8 b1 = *(const short8*)(&WhT[16 + l16][kk + quad * 8]);
      short8 b2 = *(const short8*)(&WhT[32 + l16][kk + quad * 8]);
      short8 b3 = *(const short8*)(&WhT[48 + l16][kk + quad * 8]);
      acc[0] = __builtin_amdgcn_mfma_f32_16x16x32_bf16(av, b0, acc[0], 0, 0, 0);
      acc[1] = __builtin_amdgcn_mfma_f32_16x16x32_bf16(av, b1, acc[1], 0, 0, 0);
      acc[2] = __builtin_amdgcn_mfma_f32_16x16x32_bf16(av, b2, acc[2], 0, 0, 0);
      acc[3] = __builtin_amdgcn_mfma_f32_16x16x32_bf16(av, b3, acc[3], 0, 0, 0);
    }

    // ---- epilogue: gates -> c,h; h published via L2-bypass atomic stores ----
    unsigned short* hn = hbuf + (size_t)(p ^ 1) * Bsz * Hsz;
    #pragma unroll
    for (int r = 0; r < 4; ++r) {
      float gi = acc[0][r] + bias[l16];
      float gf = acc[1][r] + bias[16 + l16];
      float gg = acc[2][r] + bias[32 + l16];
      float go = acc[3][r] + bias[48 + l16];
      float si = 1.f / (1.f + __expf(-gi));
      float sf = 1.f / (1.f + __expf(-gf));
      float tg = 1.f - 2.f / (__expf(2.f * gg) + 1.f);
      float so = 1.f / (1.f + __expf(-go));
      float cn = sf * creg[r] + si * tg;
      creg[r] = cn;
      float tc = 1.f - 2.f / (__expf(2.f * cn) + 1.f);
      __hip_atomic_store(&hn[(size_t)(rowbase + quad * 4 + r) * Hsz + hcol],
                         f2bf(so * tc), __ATOMIC_RELAXED, __HIP_MEMORY_SCOPE_AGENT);
    }

    // ---- arrive: syncthreads drains vmcnt(0) for all waves' h stores, then
    // one release fetch_add (wbl2 is ~free: nothing dirty in L2 anymore) ----
    __syncthreads();
    if (tid == 0)
      __hip_atomic_fetch_add(&flags[(bid & 7) * 16], 1u,
                             __ATOMIC_RELEASE, __HIP_MEMORY_SCOPE_AGENT);
    p ^= 1;
  }

  #pragma unroll
  for (int r = 0; r < 4; ++r)
    out[(size_t)(rowbase + quad * 4 + r) * Hsz + hcol] = creg[r];
}

extern "C" void kernel_launch(void* const* d_in, const int* in_sizes, int n_in,
                              void* d_out, int out_size, void* d_ws, size_t ws_size,
                              hipStream_t stream) {
  const float* x   = (const float*)d_in[0];
  const float* Wi  = (const float*)d_in[1];
  const float* Wh  = (const float*)d_in[2];
  const float* bih = (const float*)d_in[3];
  const float* bhh = (const float*)d_in[4];
  const float* c0  = (const float*)d_in[5];
  float* out = (float*)d_out;
  unsigned char* ws = (unsigned char*)d_ws;

  if (ws_size < WS_NEED) return;

  init_kernel<<<34052, 256, 0, stream>>>(x, Wi, ws);

  void* args[] = { (void*)&Wh, (void*)&bih, (void*)&bhh,
                   (void*)&c0, (void*)&out, (void*)&ws };
  hipLaunchCooperativeKernel((void*)lstm_persistent, dim3(256), dim3(256),
                             args, 0, stream);
}

// Round 3
// 10952.369 us; speedup vs baseline: 1.7431x; 1.1156x over previous
//
#include <hip/hip_runtime.h>
#include <stdint.h>

#define Bsz 256
#define Tsz 512
#define Isz 512
#define Hsz 1024

typedef __attribute__((ext_vector_type(8))) short short8;
typedef __attribute__((ext_vector_type(4))) float f32x4;

// ws layout
static constexpr size_t XBF_OFF  = 0;                    // x bf16 [T][B][I]   = 128 MB
static constexpr size_t WIBF_OFF = 134217728;            // W_ih bf16 [4096][512] = 4 MB
static constexpr size_t HBUF_OFF = 138412032;            // h double buf bf16 [2][B][H] = 1 MB
static constexpr size_t FLAG_OFF = 139460608;            // 8 counters, 4096 B apart = 32 KB
static constexpr size_t WS_NEED  = 139493376;

__device__ __forceinline__ unsigned short f2bf(float f) {
  union { float f; unsigned u; } v; v.f = f;
  unsigned r = v.u + 0x7fff + ((v.u >> 16) & 1);   // RNE
  return (unsigned short)(r >> 16);
}

__device__ __forceinline__ void cvt8(const float* __restrict__ s, unsigned short* __restrict__ d) {
  float4 a = *(const float4*)s;
  float4 b = *(const float4*)(s + 4);
  union { unsigned short us[8]; uint4 v; } o;
  o.us[0] = f2bf(a.x); o.us[1] = f2bf(a.y); o.us[2] = f2bf(a.z); o.us[3] = f2bf(a.w);
  o.us[4] = f2bf(b.x); o.us[5] = f2bf(b.y); o.us[6] = f2bf(b.z); o.us[7] = f2bf(b.w);
  *(uint4*)d = o.v;
}

// L2-bypassing h-fragment load: two 8-byte relaxed agent-scope atomic loads
// (sc1 -> served fresh from the coherent memory-side LLC; no buffer_inv).
__device__ __forceinline__ short8 ld_h(const unsigned short* p) {
  unsigned long long lo = __hip_atomic_load((unsigned long long*)(void*)p,
                                            __ATOMIC_RELAXED, __HIP_MEMORY_SCOPE_AGENT);
  unsigned long long hi = __hip_atomic_load((unsigned long long*)(void*)(p + 4),
                                            __ATOMIC_RELAXED, __HIP_MEMORY_SCOPE_AGENT);
  union { unsigned long long q[2]; short8 s; } u;
  u.q[0] = lo; u.q[1] = hi;
  return u.s;
}

// ---------------------------------------------------------------------------
// Init: x [B][T][I] fp32 -> xbf [T][B][I] bf16 ; W_ih fp32 -> bf16 ; zero h/flags
// ---------------------------------------------------------------------------
__global__ __launch_bounds__(256)
void init_kernel(const float* __restrict__ x, const float* __restrict__ Wi,
                 unsigned char* __restrict__ ws)
{
  unsigned short* xbf  = (unsigned short*)(ws + XBF_OFF);
  unsigned short* wibf = (unsigned short*)(ws + WIBF_OFF);
  const int bid = blockIdx.x;
  const int tid = threadIdx.x;

  if (bid < 32768) {
    const int rowid = bid * 4 + (tid >> 6);      // rowid = t*256 + b
    const int t = rowid >> 8;
    const int b = rowid & 255;
    const int i = (tid & 63) * 8;
    const float* src = x + ((size_t)b * Tsz + t) * Isz + i;
    unsigned short* dst = xbf + (size_t)rowid * Isz + i;
    cvt8(src, dst);
  } else if (bid < 32768 + 1024) {
    const size_t base = (size_t)(bid - 32768) * 2048 + (size_t)tid * 8;
    cvt8(Wi + base, wibf + base);
  } else {
    // zero h_buf (1 MB) + flags (32 KB) = 67584 x 16B chunks
    const int z = bid - 33792;                    // 0..259
    uint4 zero = make_uint4(0u, 0u, 0u, 0u);
    for (size_t j = (size_t)z * 256 + tid; j < 67584; j += (size_t)260 * 256)
      ((uint4*)(ws + HBUF_OFF))[j] = zero;
  }
}

// ---------------------------------------------------------------------------
// Persistent LSTM: 256 WGs (4 row-groups x 64 hidden-groups), 256 threads.
// Wave = 16 batch rows x 64 gate cols. 1 wave/SIMD -> latency hiding is ILP.
// ---------------------------------------------------------------------------
__global__ __launch_bounds__(256, 1)
void lstm_persistent(const float* __restrict__ Wh,
                     const float* __restrict__ b_ih, const float* __restrict__ b_hh,
                     const float* __restrict__ c0, float* __restrict__ out,
                     unsigned char* __restrict__ ws)
{
  const unsigned short* __restrict__ xbf  = (const unsigned short*)(ws + XBF_OFF);
  const unsigned short* __restrict__ wibf = (const unsigned short*)(ws + WIBF_OFF);
  unsigned short* __restrict__ hbuf = (unsigned short*)(ws + HBUF_OFF);
  unsigned* __restrict__ flags = (unsigned*)(ws + FLAG_OFF);

  __shared__ unsigned short WhT[64][1032];   // +8 pad: 2-way LDS aliasing (free)
  __shared__ float bias[64];

  const int tid  = threadIdx.x;
  const int bid  = blockIdx.x;
  const int cg   = bid & 63;
  const int rg   = bid >> 6;
  const int wv   = tid >> 6;
  const int lane = tid & 63;
  const int l16  = lane & 15;
  const int quad = lane >> 4;

  // ---- stage W_hh slice (fp32 -> bf16) into LDS ----
  {
    const int n  = tid >> 2;
    const int q  = n >> 4, u = n & 15;
    const int gc = q * 1024 + cg * 16 + u;
    const int k0 = (tid & 3) * 256;
    const float* src = Wh + (size_t)gc * Hsz + k0;
    unsigned short* dst = &WhT[n][k0];
    #pragma unroll 4
    for (int k = 0; k < 256; k += 8) cvt8(src + k, dst + k);
  }
  if (tid < 64) {
    const int q = tid >> 4, u = tid & 15;
    const int gc = q * 1024 + cg * 16 + u;
    bias[tid] = b_ih[gc] + b_hh[gc];
  }
  __syncthreads();

  const int rowbase = rg * 64 + wv * 16;
  const int arow    = rowbase + l16;
  const int hcol    = cg * 16 + l16;

  // loop-invariant biases in registers
  const float bi_r = bias[l16];
  const float bf_r = bias[16 + l16];
  const float bg_r = bias[32 + l16];
  const float bo_r = bias[48 + l16];

  float creg[4];
  #pragma unroll
  for (int r = 0; r < 4; ++r)
    creg[r] = c0[(size_t)(rowbase + quad * 4 + r) * Hsz + hcol];

  const unsigned short* bp[4];
  #pragma unroll
  for (int q = 0; q < 4; ++q)
    bp[q] = wibf + (size_t)(q * 1024 + cg * 16 + l16) * Isz + quad * 8;

  int p = 0;
  for (int t = 0; t < Tsz; ++t) {
    const unsigned short* xt = xbf  + (size_t)t * Bsz * Isz + (size_t)arow * Isz + quad * 8;
    const unsigned short* hp = hbuf + (size_t)p * Bsz * Hsz + (size_t)arow * Hsz + quad * 8;

    f32x4 acc[4];
    #pragma unroll
    for (int q = 0; q < 4; ++q) acc[q] = (f32x4){0.f, 0.f, 0.f, 0.f};

    // ---- x @ W_ih^T partial (no h dependency -> overlaps arrival skew) ----
    #pragma unroll 4
    for (int ks = 0; ks < 16; ++ks) {
      const int kk = ks * 32;
      short8 av = *(const short8*)(xt + kk);
      short8 b0 = *(const short8*)(bp[0] + kk);
      short8 b1 = *(const short8*)(bp[1] + kk);
      short8 b2 = *(const short8*)(bp[2] + kk);
      short8 b3 = *(const short8*)(bp[3] + kk);
      acc[0] = __builtin_amdgcn_mfma_f32_16x16x32_bf16(av, b0, acc[0], 0, 0, 0);
      acc[1] = __builtin_amdgcn_mfma_f32_16x16x32_bf16(av, b1, acc[1], 0, 0, 0);
      acc[2] = __builtin_amdgcn_mfma_f32_16x16x32_bf16(av, b2, acc[2], 0, 0, 0);
      acc[3] = __builtin_amdgcn_mfma_f32_16x16x32_bf16(av, b3, acc[3], 0, 0, 0);
    }

    // ---- wait: 8 lanes poll 8 spread counters (no redundant pollers) ----
    if (t > 0 && tid < 8) {
      const unsigned tgt = 32u * (unsigned)t;
      unsigned* f = &flags[tid * 1024];          // 4 KB apart -> distinct channels
      while (__hip_atomic_load(f, __ATOMIC_RELAXED, __HIP_MEMORY_SCOPE_AGENT) < tgt)
        ;
    }
    __syncthreads();

    // ---- h @ W_hh^T, depth-8 ILP prefetch on the LLC h loads ----
    short8 hv[8];
    #pragma unroll
    for (int j = 0; j < 8; ++j) hv[j] = ld_h(hp + j * 32);

    #pragma unroll
    for (int ks = 0; ks < 32; ++ks) {
      short8 av = hv[ks & 7];
      if (ks + 8 < 32) hv[ks & 7] = ld_h(hp + (ks + 8) * 32);
      const int kk = ks * 32;
      short8 b0 = *(const short8*)(&WhT[l16     ][kk + quad * 8]);
      short8 b1 = *(const short8*)(&WhT[16 + l16][kk + quad * 8]);
      short8 b2 = *(const short8*)(&WhT[32 + l16][kk + quad * 8]);
      short8 b3 = *(const short8*)(&WhT[48 + l16][kk + quad * 8]);
      acc[0] = __builtin_amdgcn_mfma_f32_16x16x32_bf16(av, b0, acc[0], 0, 0, 0);
      acc[1] = __builtin_amdgcn_mfma_f32_16x16x32_bf16(av, b1, acc[1], 0, 0, 0);
      acc[2] = __builtin_amdgcn_mfma_f32_16x16x32_bf16(av, b2, acc[2], 0, 0, 0);
      acc[3] = __builtin_amdgcn_mfma_f32_16x16x32_bf16(av, b3, acc[3], 0, 0, 0);
    }

    // ---- epilogue: gates -> c,h; h published via sc1 (LLC) atomic stores ----
    unsigned short* hn = hbuf + (size_t)(p ^ 1) * Bsz * Hsz;
    #pragma unroll
    for (int r = 0; r < 4; ++r) {
      float gi = acc[0][r] + bi_r;
      float gf = acc[1][r] + bf_r;
      float gg = acc[2][r] + bg_r;
      float go = acc[3][r] + bo_r;
      float si = 1.f / (1.f + __expf(-gi));
      float sf = 1.f / (1.f + __expf(-gf));
      float tg = 1.f - 2.f / (__expf(2.f * gg) + 1.f);
      float so = 1.f / (1.f + __expf(-go));
      float cn = sf * creg[r] + si * tg;
      creg[r] = cn;
      float tc = 1.f - 2.f / (__expf(2.f * cn) + 1.f);
      __hip_atomic_store(&hn[(size_t)(rowbase + quad * 4 + r) * Hsz + hcol],
                         f2bf(so * tc), __ATOMIC_RELAXED, __HIP_MEMORY_SCOPE_AGENT);
    }

    // ---- arrive: syncthreads drains vmcnt(0) (h stores ACKed at LLC), then a
    // RELAXED fetch_add. No release -> no buffer_wbl2 L2 tag-walk. The h
    // stores are sc1 themselves, so there is nothing for wbl2 to flush. ----
    __syncthreads();
    __atomic_signal_fence(__ATOMIC_SEQ_CST);     // compiler-only ordering
    if (tid == 0)
      __hip_atomic_fetch_add(&flags[(bid & 7) * 1024], 1u,
                             __ATOMIC_RELAXED, __HIP_MEMORY_SCOPE_AGENT);
    p ^= 1;
  }

  #pragma unroll
  for (int r = 0; r < 4; ++r)
    out[(size_t)(rowbase + quad * 4 + r) * Hsz + hcol] = creg[r];
}

extern "C" void kernel_launch(void* const* d_in, const int* in_sizes, int n_in,
                              void* d_out, int out_size, void* d_ws, size_t ws_size,
                              hipStream_t stream) {
  const float* x   = (const float*)d_in[0];
  const float* Wi  = (const float*)d_in[1];
  const float* Wh  = (const float*)d_in[2];
  const float* bih = (const float*)d_in[3];
  const float* bhh = (const float*)d_in[4];
  const float* c0  = (const float*)d_in[5];
  float* out = (float*)d_out;
  unsigned char* ws = (unsigned char*)d_ws;

  if (ws_size < WS_NEED) return;

  init_kernel<<<34052, 256, 0, stream>>>(x, Wi, ws);

  void* args[] = { (void*)&Wh, (void*)&bih, (void*)&bhh,
                   (void*)&c0, (void*)&out, (void*)&ws };
  hipLaunchCooperativeKernel((void*)lstm_persistent, dim3(256), dim3(256),
                             args, 0, stream);
}